// Round 8
// baseline (272.117 us; speedup 1.0000x reference)
//
#include <hip/hip_runtime.h>
#include <math.h>

#define NNODE 65536
#define NEDGE 1048576
#define NGRAPH 128
#define NPG 512
#define EPG 8192

typedef _Float16 f16x8 __attribute__((ext_vector_type(8)));
typedef _Float16 f16x4 __attribute__((ext_vector_type(4)));
typedef float f32x4 __attribute__((ext_vector_type(4)));

// ---- CSR build (block per graph) + init: alive, gate, dinv(L1), hg=0 ----

__global__ __launch_bounds__(512) void k_csr(const int* __restrict__ srcE, const int* __restrict__ dstE,
                                             int* __restrict__ rp, int* __restrict__ csr,
                                             float* __restrict__ gate, int* __restrict__ alive,
                                             float* __restrict__ dinv, float* __restrict__ hg) {
    __shared__ int cnt[512];
    __shared__ int wsum[8];
    int g = blockIdx.x, t = threadIdx.x;
    int nd = g * NPG + t;
    cnt[t] = 0;
    gate[nd] = 1.f;
    alive[nd] = nd;
    if (t < 256) hg[g * 256 + t] = 0.f;
    __syncthreads();
    int ebase = g * EPG;
    int dl[16];
    for (int i = 0; i < 16; ++i) {
        int e = ebase + t + i * 512;
        int d = dstE[e] - g * NPG;
        dl[i] = d;
        atomicAdd(&cnt[d], 1);
    }
    __syncthreads();
    int v = cnt[t];
    dinv[nd] = rsqrtf(1.f + (float)v);
    int lane = t & 63, wid = t >> 6;
    int x = v;
    for (int o = 1; o < 64; o <<= 1) {
        int n = __shfl_up(x, o);
        if (lane >= o) x += n;
    }
    if (lane == 63) wsum[wid] = x;
    __syncthreads();
    if (t == 0) {
        int run = 0;
        for (int i = 0; i < 8; ++i) { int s = wsum[i]; wsum[i] = run; run += s; }
    }
    __syncthreads();
    int incl = x + wsum[wid];
    int excl = incl - v;
    rp[nd] = ebase + excl;
    if (g == NGRAPH - 1 && t == 511) rp[NNODE] = NEDGE;
    cnt[t] = excl;
    __syncthreads();
    for (int i = 0; i < 16; ++i) {
        int e = ebase + t + i * 512;
        int pos = atomicAdd(&cnt[dl[i]], 1);
        csr[ebase + pos] = srcE[e];
    }
}

// ---- one-time setup: W->fragment fp16 hi/lo (blocks 0-191) + pnorm (block 192) ----

__global__ __launch_bounds__(256) void k_setup(const float* __restrict__ W0, const float* __restrict__ W1,
                                               const float* __restrict__ W2, _Float16* __restrict__ wh,
                                               _Float16* __restrict__ wl,
                                               const float* __restrict__ p0, const float* __restrict__ p1,
                                               const float* __restrict__ p2, float* __restrict__ qinv) {
    if (blockIdx.x == 192) {
        int t = threadIdx.x;
        if (t < 192) {
            int w = t >> 6, lane = t & 63;
            const float* P = (w == 0) ? p0 : (w == 1) ? p1 : p2;
            float s = P[lane] * P[lane] + P[lane + 64] * P[lane + 64];
            for (int m = 32; m >= 1; m >>= 1) s += __shfl_xor(s, m);
            if (lane == 0) qinv[w] = rsqrtf(s);
        }
        return;
    }
    int l = blockIdx.x >> 6;
    int e = (blockIdx.x & 63) * 256 + threadIdx.x;
    const float* W = (l == 0) ? W0 : (l == 1) ? W1 : W2;
    int k = e >> 7, n = e & 127;
    float w = W[e];
    _Float16 hi = (_Float16)w;
    _Float16 lo = (_Float16)((w - (float)hi) * 2048.0f);
    int nt = n >> 4, nn = n & 15, ks = k >> 5, quad = (k & 31) >> 3, j = k & 7;
    int off = l * 16384 + ((nt * 4 + ks) * 64 + (quad * 16 + nn)) * 8 + j;
    wh[off] = hi;
    wl[off] = lo;
}

// ---- split-fp16 MFMA GEMM v3: graph-affine block mapping ----

#define CVT8(hi8, lo8, a0, a1, a2, a3, a4, a5, a6, a7)                         \
    {                                                                           \
        _Float16 q0 = (_Float16)a0, q1 = (_Float16)a1, q2 = (_Float16)a2,       \
                 q3 = (_Float16)a3, q4 = (_Float16)a4, q5 = (_Float16)a5,       \
                 q6 = (_Float16)a6, q7 = (_Float16)a7;                          \
        hi8 = (f16x8){q0, q1, q2, q3, q4, q5, q6, q7};                          \
        lo8 = (f16x8){(_Float16)((a0 - (float)q0) * 2048.f),                    \
                      (_Float16)((a1 - (float)q1) * 2048.f),                    \
                      (_Float16)((a2 - (float)q2) * 2048.f),                    \
                      (_Float16)((a3 - (float)q3) * 2048.f),                    \
                      (_Float16)((a4 - (float)q4) * 2048.f),                    \
                      (_Float16)((a5 - (float)q5) * 2048.f),                    \
                      (_Float16)((a6 - (float)q6) * 2048.f),                    \
                      (_Float16)((a7 - (float)q7) * 2048.f)};                   \
    }

__global__ __launch_bounds__(256, 2) void k_gemm(const float* __restrict__ x0, const _Float16* __restrict__ xh,
                                                 const _Float16* __restrict__ xl, const _Float16* __restrict__ wh,
                                                 const _Float16* __restrict__ wl, const float* __restrict__ gate,
                                                 const int* __restrict__ alive, float* __restrict__ h,
                                                 int srcF32, int perg) {
    __shared__ _Float16 aH[128 * 72];
    __shared__ _Float16 aL[128 * 72];
    __shared__ _Float16 bH[8192];
    __shared__ _Float16 bL[8192];
    int t = threadIdx.x;
    int lane = t & 63;
    int wv = t >> 6;
    int quad = lane >> 4, mm = lane & 15;
    int gg = blockIdx.x & 127;
    int cc0 = blockIdx.x >> 7;
    int rowbase = gg * perg + cc0 * 128;

    f32x4 accH[2][8], accM[2][8];
    for (int a = 0; a < 2; ++a)
        for (int b = 0; b < 8; ++b) {
            accH[a][b] = (f32x4){0.f, 0.f, 0.f, 0.f};
            accM[a][b] = (f32x4){0.f, 0.f, 0.f, 0.f};
        }

    for (int kh = 0; kh < 2; ++kh) {
        if (kh) __syncthreads();
        for (int pp = 0; pp < 4; ++pp) {
            int seg = t + pp * 256;
            int nt = seg >> 7, ksl = (seg >> 6) & 1, ln = seg & 63;
            int goff = ((nt * 4 + kh * 2 + ksl) * 64 + ln) * 8;
            *(uint4*)(bH + seg * 8) = *(const uint4*)(wh + goff);
            *(uint4*)(bL + seg * 8) = *(const uint4*)(wl + goff);
        }
        for (int pp = 0; pp < 4; ++pp) {
            int c = t + pp * 256;
            int r = c >> 3, ch = c & 7;
            int node = alive[rowbase + r];
            size_t src = (size_t)node * 128 + kh * 64 + ch * 8;
            f16x8 hi8, lo8;
            if (srcF32) {
                float4 v0 = *(const float4*)(x0 + src);
                float4 v1 = *(const float4*)(x0 + src + 4);
                CVT8(hi8, lo8, v0.x, v0.y, v0.z, v0.w, v1.x, v1.y, v1.z, v1.w);
            } else {
                hi8 = *(const f16x8*)(xh + src);
                lo8 = *(const f16x8*)(xl + src);
            }
            *(f16x8*)(aH + r * 72 + ch * 8) = hi8;
            *(f16x8*)(aL + r * 72 + ch * 8) = lo8;
        }
        __syncthreads();

        for (int ksl = 0; ksl < 2; ++ksl) {
            f16x8 Ah[2], Al[2];
            for (int mt = 0; mt < 2; ++mt) {
                int row = wv * 32 + mt * 16 + mm;
                Ah[mt] = *(const f16x8*)(aH + row * 72 + ksl * 32 + quad * 8);
                Al[mt] = *(const f16x8*)(aL + row * 72 + ksl * 32 + quad * 8);
            }
            for (int nt = 0; nt < 8; ++nt) {
                f16x8 Bh = *(const f16x8*)(bH + ((nt * 2 + ksl) * 64 + lane) * 8);
                f16x8 Bl = *(const f16x8*)(bL + ((nt * 2 + ksl) * 64 + lane) * 8);
                for (int mt = 0; mt < 2; ++mt) {
                    accH[mt][nt] = __builtin_amdgcn_mfma_f32_16x16x32_f16(Ah[mt], Bh, accH[mt][nt], 0, 0, 0);
                    accM[mt][nt] = __builtin_amdgcn_mfma_f32_16x16x32_f16(Ah[mt], Bl, accM[mt][nt], 0, 0, 0);
                    accM[mt][nt] = __builtin_amdgcn_mfma_f32_16x16x32_f16(Al[mt], Bh, accM[mt][nt], 0, 0, 0);
                }
            }
        }
    }

    for (int mt = 0; mt < 2; ++mt)
        for (int i = 0; i < 4; ++i) {
            int rl = wv * 32 + mt * 16 + quad * 4 + i;
            int node = alive[rowbase + rl];
            float g = gate[node];
            float* hr = h + (size_t)node * 128 + mm;
            for (int nt = 0; nt < 8; ++nt)
                hr[nt * 16] = g * (accH[mt][nt][i] + accM[mt][nt][i] * (1.f / 2048.f));
        }
}

// ---- agg L1 (proven): full-graph LDS slab, 1024 threads, (graph, half) blocks ----

__global__ __launch_bounds__(1024) void k_aggL(const float* __restrict__ h, const float* __restrict__ dinv,
                                               const int* __restrict__ rp, const int* __restrict__ csr,
                                               const int* __restrict__ alive, const float* __restrict__ bias,
                                               const float* __restrict__ p, _Float16* __restrict__ xh,
                                               _Float16* __restrict__ xl, float* __restrict__ spart, int Kp) {
    __shared__ float hsl[512 * 68];
    __shared__ float dinv_l[512];
    __shared__ float2 nbw[64][16];
    __shared__ float bias_l[64];
    __shared__ float p_l[64];
    int t = threadIdx.x;
    int g = blockIdx.x & 127;
    int fh = blockIdx.x >> 7;
    int fb = fh * 64;
    int gbase = g * NPG;

    for (int r0 = 0; r0 < 512; r0 += 128) {
        int r = r0 + (t >> 3);
        int f8 = (t & 7) * 8;
        const float* src = h + (size_t)(gbase + r) * 128 + fb + f8;
        float4 v0 = *(const float4*)(src);
        float4 v1 = *(const float4*)(src + 4);
        *(float4*)(hsl + r * 68 + f8) = v0;
        *(float4*)(hsl + r * 68 + f8 + 4) = v1;
    }
    if (t < 512) dinv_l[t] = dinv[gbase + t];
    if (t < 64) { bias_l[t] = bias[fb + t]; p_l[t] = p[fb + t]; }
    __syncthreads();

    int lane16 = t & 15;
    int qid = t >> 4;

    for (int idx = qid; idx < Kp; idx += 64) {
        int d = alive[g * Kp + idx];
        int rd = d - gbase;
        int jb = rp[d], je = rp[d + 1];
        float dvd = dinv_l[rd];
        float4 hd = *(const float4*)(hsl + rd * 68 + lane16 * 4);
        float4 acc;
        acc.x = dvd * hd.x; acc.y = dvd * hd.y; acc.z = dvd * hd.z; acc.w = dvd * hd.w;

        for (int bk = jb; bk < je; bk += 16) {
            int nk = je - bk; if (nk > 16) nk = 16;
            float wv = 0.f;
            int rs = rd;
            if (lane16 < nk) {
                rs = csr[bk + lane16] - gbase;
                wv = dinv_l[rs];
            }
            nbw[qid][lane16] = make_float2(wv, __int_as_float(rs));
            int nk4 = (nk + 3) & ~3;
            for (int k = 0; k < nk4; k += 4) {
                float2 e0 = nbw[qid][k];
                float2 e1 = nbw[qid][k + 1];
                float2 e2 = nbw[qid][k + 2];
                float2 e3 = nbw[qid][k + 3];
                float4 h0 = *(const float4*)(hsl + __float_as_int(e0.y) * 68 + lane16 * 4);
                float4 h1 = *(const float4*)(hsl + __float_as_int(e1.y) * 68 + lane16 * 4);
                float4 h2 = *(const float4*)(hsl + __float_as_int(e2.y) * 68 + lane16 * 4);
                float4 h3 = *(const float4*)(hsl + __float_as_int(e3.y) * 68 + lane16 * 4);
                acc.x = fmaf(e0.x, h0.x, acc.x); acc.y = fmaf(e0.x, h0.y, acc.y);
                acc.z = fmaf(e0.x, h0.z, acc.z); acc.w = fmaf(e0.x, h0.w, acc.w);
                acc.x = fmaf(e1.x, h1.x, acc.x); acc.y = fmaf(e1.x, h1.y, acc.y);
                acc.z = fmaf(e1.x, h1.z, acc.z); acc.w = fmaf(e1.x, h1.w, acc.w);
                acc.x = fmaf(e2.x, h2.x, acc.x); acc.y = fmaf(e2.x, h2.y, acc.y);
                acc.z = fmaf(e2.x, h2.z, acc.z); acc.w = fmaf(e2.x, h2.w, acc.w);
                acc.x = fmaf(e3.x, h3.x, acc.x); acc.y = fmaf(e3.x, h3.y, acc.y);
                acc.z = fmaf(e3.x, h3.z, acc.z); acc.w = fmaf(e3.x, h3.w, acc.w);
            }
        }

        float4 b4 = *(const float4*)(bias_l + lane16 * 4);
        float4 o;
        o.x = fmaxf(fmaf(dvd, acc.x, b4.x), 0.f);
        o.y = fmaxf(fmaf(dvd, acc.y, b4.y), 0.f);
        o.z = fmaxf(fmaf(dvd, acc.z, b4.z), 0.f);
        o.w = fmaxf(fmaf(dvd, acc.w, b4.w), 0.f);

        _Float16 q0 = (_Float16)o.x, q1 = (_Float16)o.y, q2 = (_Float16)o.z, q3 = (_Float16)o.w;
        f16x4 oh = {q0, q1, q2, q3};
        f16x4 ol = {(_Float16)((o.x - (float)q0) * 2048.f), (_Float16)((o.y - (float)q1) * 2048.f),
                    (_Float16)((o.z - (float)q2) * 2048.f), (_Float16)((o.w - (float)q3) * 2048.f)};
        *(f16x4*)(xh + (size_t)d * 128 + fb + lane16 * 4) = oh;
        *(f16x4*)(xl + (size_t)d * 128 + fb + lane16 * 4) = ol;

        float4 p4 = *(const float4*)(p_l + lane16 * 4);
        float ps = o.x * p4.x + o.y * p4.y + o.z * p4.z + o.w * p4.w;
        ps += __shfl_xor(ps, 1);
        ps += __shfl_xor(ps, 2);
        ps += __shfl_xor(ps, 4);
        ps += __shfl_xor(ps, 8);
        if (lane16 == 0) spart[(size_t)fh * NNODE + d] = ps;
    }
}

// ---- agg L2/L3 (R7 new): alive-compacted LDS slab + node->slot map ----
// Same proven 256-block x 1024-thread (graph, half) geometry as k_aggL, but only
// the Kp alive rows are staged (Kp<=256 -> 69.6 KB slab). Neighbors resolve via
// map_l[512]; dead neighbors have dinv 0 (w=0) and alias slot 0 harmlessly.
// Replaces the ~12.2 TB/s global vector-gather path for L2/L3.

__global__ __launch_bounds__(1024) void k_aggS(const float* __restrict__ h, const float* __restrict__ dinv,
                                               const int* __restrict__ rp, const int* __restrict__ csr,
                                               const int* __restrict__ alive, const float* __restrict__ bias,
                                               const float* __restrict__ p, _Float16* __restrict__ xh,
                                               _Float16* __restrict__ xl, float* __restrict__ spart, int Kp) {
    __shared__ float slab[256 * 68];
    __shared__ float dinv_l[512];
    __shared__ int   map_l[512];
    __shared__ float2 nbw[64][16];
    __shared__ float bias_l[64];
    __shared__ float p_l[64];
    int t = threadIdx.x;
    int g = blockIdx.x & 127;
    int fh = blockIdx.x >> 7;
    int fb = fh * 64;
    int gbase = g * NPG;

    if (t < 512) { dinv_l[t] = dinv[gbase + t]; map_l[t] = 0; }
    if (t < 64) { bias_l[t] = bias[fb + t]; p_l[t] = p[fb + t]; }
    for (int r0 = 0; r0 < Kp; r0 += 128) {
        int r = r0 + (t >> 3);
        if (r < Kp) {
            int node = alive[g * Kp + r];
            int f8 = (t & 7) * 8;
            const float* src = h + (size_t)node * 128 + fb + f8;
            float4 v0 = *(const float4*)(src);
            float4 v1 = *(const float4*)(src + 4);
            *(float4*)(slab + r * 68 + f8) = v0;
            *(float4*)(slab + r * 68 + f8 + 4) = v1;
        }
    }
    __syncthreads();                     // map_l zeroed + slab staged
    if (t < Kp) map_l[alive[g * Kp + t] - gbase] = t;
    __syncthreads();

    int lane16 = t & 15;
    int qid = t >> 4;

    for (int idx = qid; idx < Kp; idx += 64) {
        int d = alive[g * Kp + idx];
        int rd = d - gbase;
        int jb = rp[d], je = rp[d + 1];
        float dvd = dinv_l[rd];
        float4 hd = *(const float4*)(slab + idx * 68 + lane16 * 4);
        float4 acc;
        acc.x = dvd * hd.x; acc.y = dvd * hd.y; acc.z = dvd * hd.z; acc.w = dvd * hd.w;

        for (int bk = jb; bk < je; bk += 16) {
            int nk = je - bk; if (nk > 16) nk = 16;
            float wv = 0.f;
            int sl = idx;                // pad: w=0, self slot
            if (lane16 < nk) {
                int rs = csr[bk + lane16] - gbase;
                wv = dinv_l[rs];         // 0 for dead -> slot value irrelevant
                sl = map_l[rs];
            }
            nbw[qid][lane16] = make_float2(wv, __int_as_float(sl));
            int nk4 = (nk + 3) & ~3;
            for (int k = 0; k < nk4; k += 4) {
                float2 e0 = nbw[qid][k];
                float2 e1 = nbw[qid][k + 1];
                float2 e2 = nbw[qid][k + 2];
                float2 e3 = nbw[qid][k + 3];
                float4 h0 = *(const float4*)(slab + __float_as_int(e0.y) * 68 + lane16 * 4);
                float4 h1 = *(const float4*)(slab + __float_as_int(e1.y) * 68 + lane16 * 4);
                float4 h2 = *(const float4*)(slab + __float_as_int(e2.y) * 68 + lane16 * 4);
                float4 h3 = *(const float4*)(slab + __float_as_int(e3.y) * 68 + lane16 * 4);
                acc.x = fmaf(e0.x, h0.x, acc.x); acc.y = fmaf(e0.x, h0.y, acc.y);
                acc.z = fmaf(e0.x, h0.z, acc.z); acc.w = fmaf(e0.x, h0.w, acc.w);
                acc.x = fmaf(e1.x, h1.x, acc.x); acc.y = fmaf(e1.x, h1.y, acc.y);
                acc.z = fmaf(e1.x, h1.z, acc.z); acc.w = fmaf(e1.x, h1.w, acc.w);
                acc.x = fmaf(e2.x, h2.x, acc.x); acc.y = fmaf(e2.x, h2.y, acc.y);
                acc.z = fmaf(e2.x, h2.z, acc.z); acc.w = fmaf(e2.x, h2.w, acc.w);
                acc.x = fmaf(e3.x, h3.x, acc.x); acc.y = fmaf(e3.x, h3.y, acc.y);
                acc.z = fmaf(e3.x, h3.z, acc.z); acc.w = fmaf(e3.x, h3.w, acc.w);
            }
        }

        float4 b4 = *(const float4*)(bias_l + lane16 * 4);
        float4 o;
        o.x = fmaxf(fmaf(dvd, acc.x, b4.x), 0.f);
        o.y = fmaxf(fmaf(dvd, acc.y, b4.y), 0.f);
        o.z = fmaxf(fmaf(dvd, acc.z, b4.z), 0.f);
        o.w = fmaxf(fmaf(dvd, acc.w, b4.w), 0.f);

        _Float16 q0 = (_Float16)o.x, q1 = (_Float16)o.y, q2 = (_Float16)o.z, q3 = (_Float16)o.w;
        f16x4 oh = {q0, q1, q2, q3};
        f16x4 ol = {(_Float16)((o.x - (float)q0) * 2048.f), (_Float16)((o.y - (float)q1) * 2048.f),
                    (_Float16)((o.z - (float)q2) * 2048.f), (_Float16)((o.w - (float)q3) * 2048.f)};
        *(f16x4*)(xh + (size_t)d * 128 + fb + lane16 * 4) = oh;
        *(f16x4*)(xl + (size_t)d * 128 + fb + lane16 * 4) = ol;

        float4 p4 = *(const float4*)(p_l + lane16 * 4);
        float ps = o.x * p4.x + o.y * p4.y + o.z * p4.z + o.w * p4.w;
        ps += __shfl_xor(ps, 1);
        ps += __shfl_xor(ps, 2);
        ps += __shfl_xor(ps, 4);
        ps += __shfl_xor(ps, 8);
        if (lane16 == 0) spart[(size_t)fh * NNODE + d] = ps;
    }
}

// ---- pool: spart halves -> sigmoid (all layers); radix top-k; readout; next dinv ----

__global__ __launch_bounds__(512) void k_pool(const _Float16* __restrict__ xh, const _Float16* __restrict__ xl,
                                              const float* __restrict__ spart, const float* __restrict__ qinv,
                                              int lidx, float* __restrict__ gate,
                                              int* __restrict__ alive, float* __restrict__ hg,
                                              const int* __restrict__ rp, const int* __restrict__ csr,
                                              float* __restrict__ dinv, int K, int last) {
    __shared__ unsigned hist[1024];
    __shared__ unsigned wsum[8];
    __shared__ float cand[512];
    __shared__ int ad[256];
    __shared__ float ag[256];
    __shared__ float red[1024];
    __shared__ int m_new[512];
    __shared__ int scnt;
    __shared__ unsigned ccnt;
    __shared__ unsigned tbb, tbab;
    __shared__ float thrS;
    int t = threadIdx.x, g = blockIdx.x;
    int gbase = g * NPG;
    int d = gbase + t;

    float odv = dinv[d];
    int m = odv > 0.f;
    float z = spart[d] + spart[NNODE + d];
    float sc = 1.f / (1.f + expf(-z * qinv[lidx]));
    unsigned bits = m ? __float_as_uint(sc) : 0u;
    unsigned bucket = bits >> 21;
    hist[t] = 0; hist[t + 512] = 0;
    if (t == 0) { scnt = 0; ccnt = 0; }
    __syncthreads();
    atomicAdd(&hist[bucket], 1u);
    __syncthreads();
    unsigned a0 = hist[1023 - 2 * t];
    unsigned a1 = hist[1022 - 2 * t];
    unsigned pair = a0 + a1;
    unsigned v = pair;
    for (int o = 1; o < 64; o <<= 1) {
        unsigned n = __shfl_up(v, o);
        if ((t & 63) >= o) v += n;
    }
    if ((t & 63) == 63) wsum[t >> 6] = v;
    __syncthreads();
    if (t == 0) {
        unsigned run = 0;
        for (int i = 0; i < 8; ++i) { unsigned x = wsum[i]; wsum[i] = run; run += x; }
    }
    __syncthreads();
    unsigned incl = v + wsum[t >> 6];
    unsigned excl = incl - pair;
    unsigned uK = (unsigned)K;
    if (excl < uK && excl + a0 >= uK) { tbb = 1023 - 2 * t; tbab = excl; }
    else if (excl + a0 < uK && incl >= uK) { tbb = 1022 - 2 * t; tbab = excl + a0; }
    __syncthreads();
    unsigned bsel = tbb;
    unsigned r = uK - tbab;
    if (m && bucket == bsel) {
        unsigned pos = atomicAdd(&ccnt, 1u);
        cand[pos] = sc;
    }
    __syncthreads();
    unsigned c = ccnt;
    if (t < (int)c) {
        float vv = cand[t];
        unsigned gt = 0;
        for (unsigned i = 0; i < c; ++i) gt += (cand[i] > vv) ? 1u : 0u;
        if (gt == r - 1) thrS = vv;
    }
    __syncthreads();
    float thr = thrS;

    int nm = (m && sc >= thr) ? 1 : 0;
    gate[d] = nm ? sc : 0.f;
    m_new[t] = nm;
    if (nm) {
        int pos = atomicAdd(&scnt, 1);
        if (pos < K) {
            alive[g * K + pos] = d;
            ad[pos] = d;
            ag[pos] = sc;
        }
    }
    __syncthreads();

    if (!last) {
        float nd = 0.f;
        if (nm) {
            int jb = rp[d], je = rp[d + 1];
            int sum = 0;
            for (int j = jb; j < je; ++j) sum += m_new[csr[j] - gbase];
            nd = rsqrtf(1.f + (float)sum);
        }
        dinv[d] = nd;
    }

    int f = t & 127, c2 = t >> 7;
    float mx = 0.f, sm = 0.f;
#define REC(node) ((float)xh[(size_t)(node)*128 + f] + (float)xl[(size_t)(node)*128 + f] * (1.f / 2048.f))
    for (int j = c2; j < K; j += 16) {
        float v0 = REC(ad[j]) * ag[j];
        float v1 = REC(ad[j + 4]) * ag[j + 4];
        float v2 = REC(ad[j + 8]) * ag[j + 8];
        float v3 = REC(ad[j + 12]) * ag[j + 12];
        mx = fmaxf(fmaxf(fmaxf(mx, v0), fmaxf(v1, v2)), v3);
        sm += v0 + v1 + v2 + v3;
    }
#undef REC
    red[t] = mx; red[512 + t] = sm;
    __syncthreads();
    if (c2 == 0) {
        for (int cc = 1; cc < 4; ++cc) {
            mx = fmaxf(mx, red[cc * 128 + f]);
            sm += red[512 + cc * 128 + f];
        }
        hg[g * 256 + f] += mx;
        hg[g * 256 + 128 + f] += sm / (float)K;
    }
}

// ---------------- fused MLP head ----------------

__global__ __launch_bounds__(256) void k_mlp(const float* __restrict__ inp_c, const float* __restrict__ hg,
                                             const float* __restrict__ We, const float* __restrict__ Wa,
                                             const float* __restrict__ ba, const float* __restrict__ Wb,
                                             const float* __restrict__ bb, const float* __restrict__ Wc,
                                             float* __restrict__ out) {
    __shared__ float fus[320];
    __shared__ float h1[256];
    __shared__ float h2[128];
    int t = threadIdx.x, g = blockIdx.x;
    if (t < 64) {
        float a = 0.f;
        for (int j = 0; j < 64; ++j) a = fmaf(inp_c[g * 64 + j], We[j * 64 + t], a);
        fus[t] = fmaxf(a, 0.f);
    }
    fus[64 + t] = hg[g * 256 + t];
    __syncthreads();
    {
        float a = ba[t];
        for (int j = 0; j < 320; ++j) a = fmaf(fus[j], Wa[j * 256 + t], a);
        h1[t] = fmaxf(a, 0.f);
    }
    __syncthreads();
    if (t < 128) {
        float a = bb[t];
        for (int j = 0; j < 256; ++j) a = fmaf(h1[j], Wb[j * 128 + t], a);
        h2[t] = fmaxf(a, 0.f);
    }
    __syncthreads();
    if (t == 0) {
        float a = 0.f;
        for (int j = 0; j < 128; ++j) a = fmaf(h2[j], Wc[j], a);
        out[g] = a;
    }
}

// ---------------- launch ----------------

extern "C" void kernel_launch(void* const* d_in, const int* in_sizes, int n_in,
                              void* d_out, int out_size, void* d_ws, size_t ws_size,
                              hipStream_t stream) {
    (void)in_sizes; (void)n_in; (void)out_size; (void)ws_size;
    const float* x_in  = (const float*)d_in[0];
    const float* inp_c = (const float*)d_in[1];
    const int*   ei    = (const int*)d_in[2];
    const int* srcE = ei;
    const int* dstE = ei + NEDGE;
    const float* Wl[3] = {(const float*)d_in[4], (const float*)d_in[6], (const float*)d_in[8]};
    const float* bl[3] = {(const float*)d_in[5], (const float*)d_in[7], (const float*)d_in[9]};
    const float* Pl[3] = {(const float*)d_in[10], (const float*)d_in[11], (const float*)d_in[12]};
    const float* We = (const float*)d_in[13];
    const float* Wa = (const float*)d_in[14];
    const float* ba = (const float*)d_in[15];
    const float* Wb = (const float*)d_in[16];
    const float* bb = (const float*)d_in[17];
    const float* Wc = (const float*)d_in[18];
    float* out = (float*)d_out;

    char* w = (char*)d_ws;
    size_t off = 0;
    auto alloc = [&](size_t bytes) -> void* {
        void* p = w + off;
        off = (off + bytes + 255) & ~(size_t)255;
        return p;
    };
    int*   rp    = (int*)alloc((NNODE + 1) * 4);
    int*   csr   = (int*)alloc(NEDGE * 4);
    float* dinv  = (float*)alloc(NNODE * 4);
    float* gate  = (float*)alloc(NNODE * 4);
    float* spart = (float*)alloc((size_t)2 * NNODE * 4);
    float* qinv  = (float*)alloc(256);
    int*   alive = (int*)alloc(NNODE * 4);
    float* hbuf  = (float*)alloc((size_t)NNODE * 128 * 4);
    _Float16* xh = (_Float16*)alloc((size_t)NNODE * 128 * 2);
    _Float16* xl = (_Float16*)alloc((size_t)NNODE * 128 * 2);
    float* hg    = (float*)alloc(NGRAPH * 256 * 4);
    _Float16* wfh = (_Float16*)alloc(3 * 16384 * 2);
    _Float16* wfl = (_Float16*)alloc(3 * 16384 * 2);

    k_setup<<<193, 256, 0, stream>>>(Wl[0], Wl[1], Wl[2], wfh, wfl, Pl[0], Pl[1], Pl[2], qinv);
    k_csr<<<NGRAPH, 512, 0, stream>>>(srcE, dstE, rp, csr, gate, alive, dinv, hg);

    const int rows_in[3] = {65536, 32768, 16384};
    const int Ks[3] = {256, 128, 64};
    const int Kp[3] = {512, 256, 128};
    for (int l = 0; l < 3; ++l) {
        k_gemm<<<rows_in[l] / 128, 256, 0, stream>>>(x_in, xh, xl, wfh + l * 16384, wfl + l * 16384,
                                                     gate, alive, hbuf, l == 0, rows_in[l] / 128);
        if (l == 0) {
            k_aggL<<<256, 1024, 0, stream>>>(hbuf, dinv, rp, csr, alive, bl[l], Pl[l],
                                             xh, xl, spart, Kp[l]);
        } else {
            k_aggS<<<256, 1024, 0, stream>>>(hbuf, dinv, rp, csr, alive, bl[l], Pl[l],
                                             xh, xl, spart, Kp[l]);
        }
        k_pool<<<NGRAPH, 512, 0, stream>>>(xh, xl, spart, qinv, l, gate, alive, hg,
                                           rp, csr, dinv, Ks[l], l == 2);
    }
    k_mlp<<<NGRAPH, 256, 0, stream>>>(inp_c, hg, We, Wa, ba, Wb, bb, Wc, out);
}

// Round 9
// 262.543 us; speedup vs baseline: 1.0365x; 1.0365x over previous
//
#include <hip/hip_runtime.h>
#include <math.h>

#define NNODE 65536
#define NEDGE 1048576
#define NGRAPH 128
#define NPG 512
#define EPG 8192

typedef _Float16 f16x8 __attribute__((ext_vector_type(8)));
typedef _Float16 f16x4 __attribute__((ext_vector_type(4)));
typedef float f32x4 __attribute__((ext_vector_type(4)));

// ---- CSR build (blocks 0-127) + one-time setup (blocks 128-224) ----
// R8: k_setup folded in as extra blocks (dispatch-count experiment).

__global__ __launch_bounds__(512) void k_csr(const int* __restrict__ srcE, const int* __restrict__ dstE,
                                             int* __restrict__ rp, int* __restrict__ csr,
                                             float* __restrict__ gate, int* __restrict__ alive,
                                             float* __restrict__ dinv, float* __restrict__ hg,
                                             const float* __restrict__ W0, const float* __restrict__ W1,
                                             const float* __restrict__ W2, _Float16* __restrict__ wh,
                                             _Float16* __restrict__ wl,
                                             const float* __restrict__ p0, const float* __restrict__ p1,
                                             const float* __restrict__ p2, float* __restrict__ qinv) {
    __shared__ int cnt[512];
    __shared__ int wsum[8];
    int t = threadIdx.x;
    if (blockIdx.x >= 128) {
        // setup path: virtual 256-thread block id vb in 0..193
        int vb = (blockIdx.x - 128) * 2 + (t >> 8);
        int tt = t & 255;
        if (vb == 192) {
            if (tt < 192) {
                int w = tt >> 6, lane = tt & 63;
                const float* P = (w == 0) ? p0 : (w == 1) ? p1 : p2;
                float s = P[lane] * P[lane] + P[lane + 64] * P[lane + 64];
                for (int m = 32; m >= 1; m >>= 1) s += __shfl_xor(s, m);
                if (lane == 0) qinv[w] = rsqrtf(s);
            }
        } else if (vb < 192) {
            int l = vb >> 6;
            int e = (vb & 63) * 256 + tt;
            const float* W = (l == 0) ? W0 : (l == 1) ? W1 : W2;
            int k = e >> 7, n = e & 127;
            float w = W[e];
            _Float16 hi = (_Float16)w;
            _Float16 lo = (_Float16)((w - (float)hi) * 2048.0f);
            int nt = n >> 4, nn = n & 15, ks = k >> 5, quad = (k & 31) >> 3, j = k & 7;
            int off = l * 16384 + ((nt * 4 + ks) * 64 + (quad * 16 + nn)) * 8 + j;
            wh[off] = hi;
            wl[off] = lo;
        }
        return;
    }
    int g = blockIdx.x;
    int nd = g * NPG + t;
    cnt[t] = 0;
    gate[nd] = 1.f;
    alive[nd] = nd;
    if (t < 256) hg[g * 256 + t] = 0.f;
    __syncthreads();
    int ebase = g * EPG;
    int dl[16];
    for (int i = 0; i < 16; ++i) {
        int e = ebase + t + i * 512;
        int d = dstE[e] - g * NPG;
        dl[i] = d;
        atomicAdd(&cnt[d], 1);
    }
    __syncthreads();
    int v = cnt[t];
    dinv[nd] = rsqrtf(1.f + (float)v);
    int lane = t & 63, wid = t >> 6;
    int x = v;
    for (int o = 1; o < 64; o <<= 1) {
        int n = __shfl_up(x, o);
        if (lane >= o) x += n;
    }
    if (lane == 63) wsum[wid] = x;
    __syncthreads();
    if (t == 0) {
        int run = 0;
        for (int i = 0; i < 8; ++i) { int s = wsum[i]; wsum[i] = run; run += s; }
    }
    __syncthreads();
    int incl = x + wsum[wid];
    int excl = incl - v;
    rp[nd] = ebase + excl;
    if (g == NGRAPH - 1 && t == 511) rp[NNODE] = NEDGE;
    cnt[t] = excl;
    __syncthreads();
    for (int i = 0; i < 16; ++i) {
        int e = ebase + t + i * 512;
        int pos = atomicAdd(&cnt[dl[i]], 1);
        csr[ebase + pos] = srcE[e];
    }
}

// ---- split-fp16 MFMA GEMM v3: graph-affine block mapping ----

#define CVT8(hi8, lo8, a0, a1, a2, a3, a4, a5, a6, a7)                         \
    {                                                                           \
        _Float16 q0 = (_Float16)a0, q1 = (_Float16)a1, q2 = (_Float16)a2,       \
                 q3 = (_Float16)a3, q4 = (_Float16)a4, q5 = (_Float16)a5,       \
                 q6 = (_Float16)a6, q7 = (_Float16)a7;                          \
        hi8 = (f16x8){q0, q1, q2, q3, q4, q5, q6, q7};                          \
        lo8 = (f16x8){(_Float16)((a0 - (float)q0) * 2048.f),                    \
                      (_Float16)((a1 - (float)q1) * 2048.f),                    \
                      (_Float16)((a2 - (float)q2) * 2048.f),                    \
                      (_Float16)((a3 - (float)q3) * 2048.f),                    \
                      (_Float16)((a4 - (float)q4) * 2048.f),                    \
                      (_Float16)((a5 - (float)q5) * 2048.f),                    \
                      (_Float16)((a6 - (float)q6) * 2048.f),                    \
                      (_Float16)((a7 - (float)q7) * 2048.f)};                   \
    }

__global__ __launch_bounds__(256, 2) void k_gemm(const float* __restrict__ x0, const _Float16* __restrict__ xh,
                                                 const _Float16* __restrict__ xl, const _Float16* __restrict__ wh,
                                                 const _Float16* __restrict__ wl, const float* __restrict__ gate,
                                                 const int* __restrict__ alive, float* __restrict__ h,
                                                 int srcF32, int perg) {
    __shared__ _Float16 aH[128 * 72];
    __shared__ _Float16 aL[128 * 72];
    __shared__ _Float16 bH[8192];
    __shared__ _Float16 bL[8192];
    int t = threadIdx.x;
    int lane = t & 63;
    int wv = t >> 6;
    int quad = lane >> 4, mm = lane & 15;
    int gg = blockIdx.x & 127;
    int cc0 = blockIdx.x >> 7;
    int rowbase = gg * perg + cc0 * 128;

    f32x4 accH[2][8], accM[2][8];
    for (int a = 0; a < 2; ++a)
        for (int b = 0; b < 8; ++b) {
            accH[a][b] = (f32x4){0.f, 0.f, 0.f, 0.f};
            accM[a][b] = (f32x4){0.f, 0.f, 0.f, 0.f};
        }

    for (int kh = 0; kh < 2; ++kh) {
        if (kh) __syncthreads();
        for (int pp = 0; pp < 4; ++pp) {
            int seg = t + pp * 256;
            int nt = seg >> 7, ksl = (seg >> 6) & 1, ln = seg & 63;
            int goff = ((nt * 4 + kh * 2 + ksl) * 64 + ln) * 8;
            *(uint4*)(bH + seg * 8) = *(const uint4*)(wh + goff);
            *(uint4*)(bL + seg * 8) = *(const uint4*)(wl + goff);
        }
        for (int pp = 0; pp < 4; ++pp) {
            int c = t + pp * 256;
            int r = c >> 3, ch = c & 7;
            int node = alive[rowbase + r];
            size_t src = (size_t)node * 128 + kh * 64 + ch * 8;
            f16x8 hi8, lo8;
            if (srcF32) {
                float4 v0 = *(const float4*)(x0 + src);
                float4 v1 = *(const float4*)(x0 + src + 4);
                CVT8(hi8, lo8, v0.x, v0.y, v0.z, v0.w, v1.x, v1.y, v1.z, v1.w);
            } else {
                hi8 = *(const f16x8*)(xh + src);
                lo8 = *(const f16x8*)(xl + src);
            }
            *(f16x8*)(aH + r * 72 + ch * 8) = hi8;
            *(f16x8*)(aL + r * 72 + ch * 8) = lo8;
        }
        __syncthreads();

        for (int ksl = 0; ksl < 2; ++ksl) {
            f16x8 Ah[2], Al[2];
            for (int mt = 0; mt < 2; ++mt) {
                int row = wv * 32 + mt * 16 + mm;
                Ah[mt] = *(const f16x8*)(aH + row * 72 + ksl * 32 + quad * 8);
                Al[mt] = *(const f16x8*)(aL + row * 72 + ksl * 32 + quad * 8);
            }
            for (int nt = 0; nt < 8; ++nt) {
                f16x8 Bh = *(const f16x8*)(bH + ((nt * 2 + ksl) * 64 + lane) * 8);
                f16x8 Bl = *(const f16x8*)(bL + ((nt * 2 + ksl) * 64 + lane) * 8);
                for (int mt = 0; mt < 2; ++mt) {
                    accH[mt][nt] = __builtin_amdgcn_mfma_f32_16x16x32_f16(Ah[mt], Bh, accH[mt][nt], 0, 0, 0);
                    accM[mt][nt] = __builtin_amdgcn_mfma_f32_16x16x32_f16(Ah[mt], Bl, accM[mt][nt], 0, 0, 0);
                    accM[mt][nt] = __builtin_amdgcn_mfma_f32_16x16x32_f16(Al[mt], Bh, accM[mt][nt], 0, 0, 0);
                }
            }
        }
    }

    for (int mt = 0; mt < 2; ++mt)
        for (int i = 0; i < 4; ++i) {
            int rl = wv * 32 + mt * 16 + quad * 4 + i;
            int node = alive[rowbase + rl];
            float g = gate[node];
            float* hr = h + (size_t)node * 128 + mm;
            for (int nt = 0; nt < 8; ++nt)
                hr[nt * 16] = g * (accH[mt][nt][i] + accM[mt][nt][i] * (1.f / 2048.f));
        }
}

// ---- agg L1 (proven): full-graph LDS slab, 1024 threads, (graph, half) blocks ----

__global__ __launch_bounds__(1024) void k_aggL(const float* __restrict__ h, const float* __restrict__ dinv,
                                               const int* __restrict__ rp, const int* __restrict__ csr,
                                               const int* __restrict__ alive, const float* __restrict__ bias,
                                               const float* __restrict__ p, _Float16* __restrict__ xh,
                                               _Float16* __restrict__ xl, float* __restrict__ spart, int Kp) {
    __shared__ float hsl[512 * 68];
    __shared__ float dinv_l[512];
    __shared__ float2 nbw[64][16];
    __shared__ float bias_l[64];
    __shared__ float p_l[64];
    int t = threadIdx.x;
    int g = blockIdx.x & 127;
    int fh = blockIdx.x >> 7;
    int fb = fh * 64;
    int gbase = g * NPG;

    for (int r0 = 0; r0 < 512; r0 += 128) {
        int r = r0 + (t >> 3);
        int f8 = (t & 7) * 8;
        const float* src = h + (size_t)(gbase + r) * 128 + fb + f8;
        float4 v0 = *(const float4*)(src);
        float4 v1 = *(const float4*)(src + 4);
        *(float4*)(hsl + r * 68 + f8) = v0;
        *(float4*)(hsl + r * 68 + f8 + 4) = v1;
    }
    if (t < 512) dinv_l[t] = dinv[gbase + t];
    if (t < 64) { bias_l[t] = bias[fb + t]; p_l[t] = p[fb + t]; }
    __syncthreads();

    int lane16 = t & 15;
    int qid = t >> 4;

    for (int idx = qid; idx < Kp; idx += 64) {
        int d = alive[g * Kp + idx];
        int rd = d - gbase;
        int jb = rp[d], je = rp[d + 1];
        float dvd = dinv_l[rd];
        float4 hd = *(const float4*)(hsl + rd * 68 + lane16 * 4);
        float4 acc;
        acc.x = dvd * hd.x; acc.y = dvd * hd.y; acc.z = dvd * hd.z; acc.w = dvd * hd.w;

        for (int bk = jb; bk < je; bk += 16) {
            int nk = je - bk; if (nk > 16) nk = 16;
            float wv = 0.f;
            int rs = rd;
            if (lane16 < nk) {
                rs = csr[bk + lane16] - gbase;
                wv = dinv_l[rs];
            }
            nbw[qid][lane16] = make_float2(wv, __int_as_float(rs));
            int nk4 = (nk + 3) & ~3;
            for (int k = 0; k < nk4; k += 4) {
                float2 e0 = nbw[qid][k];
                float2 e1 = nbw[qid][k + 1];
                float2 e2 = nbw[qid][k + 2];
                float2 e3 = nbw[qid][k + 3];
                float4 h0 = *(const float4*)(hsl + __float_as_int(e0.y) * 68 + lane16 * 4);
                float4 h1 = *(const float4*)(hsl + __float_as_int(e1.y) * 68 + lane16 * 4);
                float4 h2 = *(const float4*)(hsl + __float_as_int(e2.y) * 68 + lane16 * 4);
                float4 h3 = *(const float4*)(hsl + __float_as_int(e3.y) * 68 + lane16 * 4);
                acc.x = fmaf(e0.x, h0.x, acc.x); acc.y = fmaf(e0.x, h0.y, acc.y);
                acc.z = fmaf(e0.x, h0.z, acc.z); acc.w = fmaf(e0.x, h0.w, acc.w);
                acc.x = fmaf(e1.x, h1.x, acc.x); acc.y = fmaf(e1.x, h1.y, acc.y);
                acc.z = fmaf(e1.x, h1.z, acc.z); acc.w = fmaf(e1.x, h1.w, acc.w);
                acc.x = fmaf(e2.x, h2.x, acc.x); acc.y = fmaf(e2.x, h2.y, acc.y);
                acc.z = fmaf(e2.x, h2.z, acc.z); acc.w = fmaf(e2.x, h2.w, acc.w);
                acc.x = fmaf(e3.x, h3.x, acc.x); acc.y = fmaf(e3.x, h3.y, acc.y);
                acc.z = fmaf(e3.x, h3.z, acc.z); acc.w = fmaf(e3.x, h3.w, acc.w);
            }
        }

        float4 b4 = *(const float4*)(bias_l + lane16 * 4);
        float4 o;
        o.x = fmaxf(fmaf(dvd, acc.x, b4.x), 0.f);
        o.y = fmaxf(fmaf(dvd, acc.y, b4.y), 0.f);
        o.z = fmaxf(fmaf(dvd, acc.z, b4.z), 0.f);
        o.w = fmaxf(fmaf(dvd, acc.w, b4.w), 0.f);

        _Float16 q0 = (_Float16)o.x, q1 = (_Float16)o.y, q2 = (_Float16)o.z, q3 = (_Float16)o.w;
        f16x4 oh = {q0, q1, q2, q3};
        f16x4 ol = {(_Float16)((o.x - (float)q0) * 2048.f), (_Float16)((o.y - (float)q1) * 2048.f),
                    (_Float16)((o.z - (float)q2) * 2048.f), (_Float16)((o.w - (float)q3) * 2048.f)};
        *(f16x4*)(xh + (size_t)d * 128 + fb + lane16 * 4) = oh;
        *(f16x4*)(xl + (size_t)d * 128 + fb + lane16 * 4) = ol;

        float4 p4 = *(const float4*)(p_l + lane16 * 4);
        float ps = o.x * p4.x + o.y * p4.y + o.z * p4.z + o.w * p4.w;
        ps += __shfl_xor(ps, 1);
        ps += __shfl_xor(ps, 2);
        ps += __shfl_xor(ps, 4);
        ps += __shfl_xor(ps, 8);
        if (lane16 == 0) spart[(size_t)fh * NNODE + d] = ps;
    }
}

// ---- agg L2/L3: alive-compacted LDS slab + node->slot map (R7) ----

__global__ __launch_bounds__(1024) void k_aggS(const float* __restrict__ h, const float* __restrict__ dinv,
                                               const int* __restrict__ rp, const int* __restrict__ csr,
                                               const int* __restrict__ alive, const float* __restrict__ bias,
                                               const float* __restrict__ p, _Float16* __restrict__ xh,
                                               _Float16* __restrict__ xl, float* __restrict__ spart, int Kp) {
    __shared__ float slab[256 * 68];
    __shared__ float dinv_l[512];
    __shared__ int   map_l[512];
    __shared__ float2 nbw[64][16];
    __shared__ float bias_l[64];
    __shared__ float p_l[64];
    int t = threadIdx.x;
    int g = blockIdx.x & 127;
    int fh = blockIdx.x >> 7;
    int fb = fh * 64;
    int gbase = g * NPG;

    if (t < 512) { dinv_l[t] = dinv[gbase + t]; map_l[t] = 0; }
    if (t < 64) { bias_l[t] = bias[fb + t]; p_l[t] = p[fb + t]; }
    for (int r0 = 0; r0 < Kp; r0 += 128) {
        int r = r0 + (t >> 3);
        if (r < Kp) {
            int node = alive[g * Kp + r];
            int f8 = (t & 7) * 8;
            const float* src = h + (size_t)node * 128 + fb + f8;
            float4 v0 = *(const float4*)(src);
            float4 v1 = *(const float4*)(src + 4);
            *(float4*)(slab + r * 68 + f8) = v0;
            *(float4*)(slab + r * 68 + f8 + 4) = v1;
        }
    }
    __syncthreads();
    if (t < Kp) map_l[alive[g * Kp + t] - gbase] = t;
    __syncthreads();

    int lane16 = t & 15;
    int qid = t >> 4;

    for (int idx = qid; idx < Kp; idx += 64) {
        int d = alive[g * Kp + idx];
        int rd = d - gbase;
        int jb = rp[d], je = rp[d + 1];
        float dvd = dinv_l[rd];
        float4 hd = *(const float4*)(slab + idx * 68 + lane16 * 4);
        float4 acc;
        acc.x = dvd * hd.x; acc.y = dvd * hd.y; acc.z = dvd * hd.z; acc.w = dvd * hd.w;

        for (int bk = jb; bk < je; bk += 16) {
            int nk = je - bk; if (nk > 16) nk = 16;
            float wv = 0.f;
            int sl = idx;
            if (lane16 < nk) {
                int rs = csr[bk + lane16] - gbase;
                wv = dinv_l[rs];
                sl = map_l[rs];
            }
            nbw[qid][lane16] = make_float2(wv, __int_as_float(sl));
            int nk4 = (nk + 3) & ~3;
            for (int k = 0; k < nk4; k += 4) {
                float2 e0 = nbw[qid][k];
                float2 e1 = nbw[qid][k + 1];
                float2 e2 = nbw[qid][k + 2];
                float2 e3 = nbw[qid][k + 3];
                float4 h0 = *(const float4*)(slab + __float_as_int(e0.y) * 68 + lane16 * 4);
                float4 h1 = *(const float4*)(slab + __float_as_int(e1.y) * 68 + lane16 * 4);
                float4 h2 = *(const float4*)(slab + __float_as_int(e2.y) * 68 + lane16 * 4);
                float4 h3 = *(const float4*)(slab + __float_as_int(e3.y) * 68 + lane16 * 4);
                acc.x = fmaf(e0.x, h0.x, acc.x); acc.y = fmaf(e0.x, h0.y, acc.y);
                acc.z = fmaf(e0.x, h0.z, acc.z); acc.w = fmaf(e0.x, h0.w, acc.w);
                acc.x = fmaf(e1.x, h1.x, acc.x); acc.y = fmaf(e1.x, h1.y, acc.y);
                acc.z = fmaf(e1.x, h1.z, acc.z); acc.w = fmaf(e1.x, h1.w, acc.w);
                acc.x = fmaf(e2.x, h2.x, acc.x); acc.y = fmaf(e2.x, h2.y, acc.y);
                acc.z = fmaf(e2.x, h2.z, acc.z); acc.w = fmaf(e2.x, h2.w, acc.w);
                acc.x = fmaf(e3.x, h3.x, acc.x); acc.y = fmaf(e3.x, h3.y, acc.y);
                acc.z = fmaf(e3.x, h3.z, acc.z); acc.w = fmaf(e3.x, h3.w, acc.w);
            }
        }

        float4 b4 = *(const float4*)(bias_l + lane16 * 4);
        float4 o;
        o.x = fmaxf(fmaf(dvd, acc.x, b4.x), 0.f);
        o.y = fmaxf(fmaf(dvd, acc.y, b4.y), 0.f);
        o.z = fmaxf(fmaf(dvd, acc.z, b4.z), 0.f);
        o.w = fmaxf(fmaf(dvd, acc.w, b4.w), 0.f);

        _Float16 q0 = (_Float16)o.x, q1 = (_Float16)o.y, q2 = (_Float16)o.z, q3 = (_Float16)o.w;
        f16x4 oh = {q0, q1, q2, q3};
        f16x4 ol = {(_Float16)((o.x - (float)q0) * 2048.f), (_Float16)((o.y - (float)q1) * 2048.f),
                    (_Float16)((o.z - (float)q2) * 2048.f), (_Float16)((o.w - (float)q3) * 2048.f)};
        *(f16x4*)(xh + (size_t)d * 128 + fb + lane16 * 4) = oh;
        *(f16x4*)(xl + (size_t)d * 128 + fb + lane16 * 4) = ol;

        float4 p4 = *(const float4*)(p_l + lane16 * 4);
        float ps = o.x * p4.x + o.y * p4.y + o.z * p4.z + o.w * p4.w;
        ps += __shfl_xor(ps, 1);
        ps += __shfl_xor(ps, 2);
        ps += __shfl_xor(ps, 4);
        ps += __shfl_xor(ps, 8);
        if (lane16 == 0) spart[(size_t)fh * NNODE + d] = ps;
    }
}

// ---- pool body (shared by the three pool kernels) ----

__device__ __forceinline__ void pool_body(const _Float16* __restrict__ xh, const _Float16* __restrict__ xl,
                                          const float* __restrict__ spart, const float* __restrict__ qinv,
                                          int lidx, float* __restrict__ gate,
                                          int* __restrict__ alive, float* __restrict__ hg,
                                          const int* __restrict__ rp, const int* __restrict__ csr,
                                          float* __restrict__ dinv, int K, int last, int g, int t) {
    __shared__ unsigned hist[1024];
    __shared__ unsigned wsum[8];
    __shared__ float cand[512];
    __shared__ int ad[256];
    __shared__ float ag[256];
    __shared__ float red[1024];
    __shared__ int m_new[512];
    __shared__ int scnt;
    __shared__ unsigned ccnt;
    __shared__ unsigned tbb, tbab;
    __shared__ float thrS;
    int gbase = g * NPG;
    int d = gbase + t;

    float odv = dinv[d];
    int m = odv > 0.f;
    float z = spart[d] + spart[NNODE + d];
    float sc = 1.f / (1.f + expf(-z * qinv[lidx]));
    unsigned bits = m ? __float_as_uint(sc) : 0u;
    unsigned bucket = bits >> 21;
    hist[t] = 0; hist[t + 512] = 0;
    if (t == 0) { scnt = 0; ccnt = 0; }
    __syncthreads();
    atomicAdd(&hist[bucket], 1u);
    __syncthreads();
    unsigned a0 = hist[1023 - 2 * t];
    unsigned a1 = hist[1022 - 2 * t];
    unsigned pair = a0 + a1;
    unsigned v = pair;
    for (int o = 1; o < 64; o <<= 1) {
        unsigned n = __shfl_up(v, o);
        if ((t & 63) >= o) v += n;
    }
    if ((t & 63) == 63) wsum[t >> 6] = v;
    __syncthreads();
    if (t == 0) {
        unsigned run = 0;
        for (int i = 0; i < 8; ++i) { unsigned x = wsum[i]; wsum[i] = run; run += x; }
    }
    __syncthreads();
    unsigned incl = v + wsum[t >> 6];
    unsigned excl = incl - pair;
    unsigned uK = (unsigned)K;
    if (excl < uK && excl + a0 >= uK) { tbb = 1023 - 2 * t; tbab = excl; }
    else if (excl + a0 < uK && incl >= uK) { tbb = 1022 - 2 * t; tbab = excl + a0; }
    __syncthreads();
    unsigned bsel = tbb;
    unsigned r = uK - tbab;
    if (m && bucket == bsel) {
        unsigned pos = atomicAdd(&ccnt, 1u);
        cand[pos] = sc;
    }
    __syncthreads();
    unsigned c = ccnt;
    if (t < (int)c) {
        float vv = cand[t];
        unsigned gt = 0;
        for (unsigned i = 0; i < c; ++i) gt += (cand[i] > vv) ? 1u : 0u;
        if (gt == r - 1) thrS = vv;
    }
    __syncthreads();
    float thr = thrS;

    int nm = (m && sc >= thr) ? 1 : 0;
    gate[d] = nm ? sc : 0.f;
    m_new[t] = nm;
    if (nm) {
        int pos = atomicAdd(&scnt, 1);
        if (pos < K) {
            alive[g * K + pos] = d;
            ad[pos] = d;
            ag[pos] = sc;
        }
    }
    __syncthreads();

    if (!last) {
        float nd = 0.f;
        if (nm) {
            int jb = rp[d], je = rp[d + 1];
            int sum = 0;
            for (int j = jb; j < je; ++j) sum += m_new[csr[j] - gbase];
            nd = rsqrtf(1.f + (float)sum);
        }
        dinv[d] = nd;
    }

    int f = t & 127, c2 = t >> 7;
    float mx = 0.f, sm = 0.f;
#define REC(node) ((float)xh[(size_t)(node)*128 + f] + (float)xl[(size_t)(node)*128 + f] * (1.f / 2048.f))
    for (int j = c2; j < K; j += 16) {
        float v0 = REC(ad[j]) * ag[j];
        float v1 = REC(ad[j + 4]) * ag[j + 4];
        float v2 = REC(ad[j + 8]) * ag[j + 8];
        float v3 = REC(ad[j + 12]) * ag[j + 12];
        mx = fmaxf(fmaxf(fmaxf(mx, v0), fmaxf(v1, v2)), v3);
        sm += v0 + v1 + v2 + v3;
    }
#undef REC
    red[t] = mx; red[512 + t] = sm;
    __syncthreads();
    if (c2 == 0) {
        for (int cc = 1; cc < 4; ++cc) {
            mx = fmaxf(mx, red[cc * 128 + f]);
            sm += red[512 + cc * 128 + f];
        }
        hg[g * 256 + f] += mx;
        hg[g * 256 + 128 + f] += sm / (float)K;
    }
}

// ---- pool L1 ----

__global__ __launch_bounds__(512) void k_poolA(const _Float16* __restrict__ xh, const _Float16* __restrict__ xl,
                                               const float* __restrict__ spart, const float* __restrict__ qinv,
                                               int lidx, float* __restrict__ gate,
                                               int* __restrict__ alive, float* __restrict__ hg,
                                               const int* __restrict__ rp, const int* __restrict__ csr,
                                               float* __restrict__ dinv, int K, int last) {
    pool_body(xh, xl, spart, qinv, lidx, gate, alive, hg, rp, csr, dinv, K, last,
              blockIdx.x, threadIdx.x);
}

// ---- pool L2 + fused gemm L3 (same-block dependency: this block wrote alive/gate) ----

__global__ __launch_bounds__(512) void k_poolB(const _Float16* __restrict__ xh, const _Float16* __restrict__ xl,
                                               const float* __restrict__ spart, const float* __restrict__ qinv,
                                               int lidx, float* __restrict__ gate,
                                               int* __restrict__ alive, float* __restrict__ hg,
                                               const int* __restrict__ rp, const int* __restrict__ csr,
                                               float* __restrict__ dinv, int K, int last,
                                               const _Float16* __restrict__ wh3, const _Float16* __restrict__ wl3,
                                               float* __restrict__ h) {
    __shared__ _Float16 aH[128 * 72];
    __shared__ _Float16 aL[128 * 72];
    __shared__ _Float16 bH[8192];
    __shared__ _Float16 bL[8192];
    int t = threadIdx.x, g = blockIdx.x;
    pool_body(xh, xl, spart, qinv, lidx, gate, alive, hg, rp, csr, dinv, K, last, g, t);
    __syncthreads();   // alive/gate for graph g committed by this block

    // gemm L3 for graph g: 128 rows (= K), 512 threads stage, waves 0-3 compute
    int lane = t & 63;
    int wv = t >> 6;                     // 0..7
    int quad = lane >> 4, mm = lane & 15;
    int rowbase = g * 128;

    f32x4 accH[2][8], accM[2][8];
    for (int a = 0; a < 2; ++a)
        for (int b = 0; b < 8; ++b) {
            accH[a][b] = (f32x4){0.f, 0.f, 0.f, 0.f};
            accM[a][b] = (f32x4){0.f, 0.f, 0.f, 0.f};
        }

    for (int kh = 0; kh < 2; ++kh) {
        if (kh) __syncthreads();
        for (int pp = 0; pp < 2; ++pp) {
            int seg = t + pp * 512;
            int nt = seg >> 7, ksl = (seg >> 6) & 1, ln = seg & 63;
            int goff = ((nt * 4 + kh * 2 + ksl) * 64 + ln) * 8;
            *(uint4*)(bH + seg * 8) = *(const uint4*)(wh3 + goff);
            *(uint4*)(bL + seg * 8) = *(const uint4*)(wl3 + goff);
        }
        for (int pp = 0; pp < 2; ++pp) {
            int c = t + pp * 512;
            int r = c >> 3, ch = c & 7;
            int node = alive[rowbase + r];
            size_t src = (size_t)node * 128 + kh * 64 + ch * 8;
            *(f16x8*)(aH + r * 72 + ch * 8) = *(const f16x8*)(xh + src);
            *(f16x8*)(aL + r * 72 + ch * 8) = *(const f16x8*)(xl + src);
        }
        __syncthreads();

        if (t < 256) {
            for (int ksl = 0; ksl < 2; ++ksl) {
                f16x8 Ah[2], Al[2];
                for (int mt = 0; mt < 2; ++mt) {
                    int row = wv * 32 + mt * 16 + mm;
                    Ah[mt] = *(const f16x8*)(aH + row * 72 + ksl * 32 + quad * 8);
                    Al[mt] = *(const f16x8*)(aL + row * 72 + ksl * 32 + quad * 8);
                }
                for (int nt = 0; nt < 8; ++nt) {
                    f16x8 Bh = *(const f16x8*)(bH + ((nt * 2 + ksl) * 64 + lane) * 8);
                    f16x8 Bl = *(const f16x8*)(bL + ((nt * 2 + ksl) * 64 + lane) * 8);
                    for (int mt = 0; mt < 2; ++mt) {
                        accH[mt][nt] = __builtin_amdgcn_mfma_f32_16x16x32_f16(Ah[mt], Bh, accH[mt][nt], 0, 0, 0);
                        accM[mt][nt] = __builtin_amdgcn_mfma_f32_16x16x32_f16(Ah[mt], Bl, accM[mt][nt], 0, 0, 0);
                        accM[mt][nt] = __builtin_amdgcn_mfma_f32_16x16x32_f16(Al[mt], Bh, accM[mt][nt], 0, 0, 0);
                    }
                }
            }
        }
    }

    if (t < 256) {
        for (int mt = 0; mt < 2; ++mt)
            for (int i = 0; i < 4; ++i) {
                int rl = wv * 32 + mt * 16 + quad * 4 + i;
                int node = alive[rowbase + rl];
                float gg = gate[node];
                float* hr = h + (size_t)node * 128 + mm;
                for (int nt = 0; nt < 8; ++nt)
                    hr[nt * 16] = gg * (accH[mt][nt][i] + accM[mt][nt][i] * (1.f / 2048.f));
            }
    }
}

// ---- pool L3 + fused MLP head (same-block dependency: hg[g] finalized here) ----

__global__ __launch_bounds__(512) void k_poolC(const _Float16* __restrict__ xh, const _Float16* __restrict__ xl,
                                               const float* __restrict__ spart, const float* __restrict__ qinv,
                                               int lidx, float* __restrict__ gate,
                                               int* __restrict__ alive, float* __restrict__ hg,
                                               const int* __restrict__ rp, const int* __restrict__ csr,
                                               float* __restrict__ dinv, int K, int last,
                                               const float* __restrict__ inp_c,
                                               const float* __restrict__ We, const float* __restrict__ Wa,
                                               const float* __restrict__ ba, const float* __restrict__ Wb,
                                               const float* __restrict__ bb, const float* __restrict__ Wc,
                                               float* __restrict__ out) {
    __shared__ float fus[320];
    __shared__ float h1[256];
    __shared__ float h2[128];
    int t = threadIdx.x, g = blockIdx.x;
    pool_body(xh, xl, spart, qinv, lidx, gate, alive, hg, rp, csr, dinv, K, last, g, t);
    __syncthreads();   // hg[g] fully accumulated (same block; L1 per-CU coherent)

    if (t < 64) {
        float a = 0.f;
        for (int j = 0; j < 64; ++j) a = fmaf(inp_c[g * 64 + j], We[j * 64 + t], a);
        fus[t] = fmaxf(a, 0.f);
    }
    if (t < 256) fus[64 + t] = hg[g * 256 + t];
    __syncthreads();
    if (t < 256) {
        float a = ba[t];
        for (int j = 0; j < 320; ++j) a = fmaf(fus[j], Wa[j * 256 + t], a);
        h1[t] = fmaxf(a, 0.f);
    }
    __syncthreads();
    if (t < 128) {
        float a = bb[t];
        for (int j = 0; j < 256; ++j) a = fmaf(h1[j], Wb[j * 128 + t], a);
        h2[t] = fmaxf(a, 0.f);
    }
    __syncthreads();
    if (t == 0) {
        float a = 0.f;
        for (int j = 0; j < 128; ++j) a = fmaf(h2[j], Wc[j], a);
        out[g] = a;
    }
}

// ---------------- launch (9 dispatches, was 12) ----------------

extern "C" void kernel_launch(void* const* d_in, const int* in_sizes, int n_in,
                              void* d_out, int out_size, void* d_ws, size_t ws_size,
                              hipStream_t stream) {
    (void)in_sizes; (void)n_in; (void)out_size; (void)ws_size;
    const float* x_in  = (const float*)d_in[0];
    const float* inp_c = (const float*)d_in[1];
    const int*   ei    = (const int*)d_in[2];
    const int* srcE = ei;
    const int* dstE = ei + NEDGE;
    const float* Wl[3] = {(const float*)d_in[4], (const float*)d_in[6], (const float*)d_in[8]};
    const float* bl[3] = {(const float*)d_in[5], (const float*)d_in[7], (const float*)d_in[9]};
    const float* Pl[3] = {(const float*)d_in[10], (const float*)d_in[11], (const float*)d_in[12]};
    const float* We = (const float*)d_in[13];
    const float* Wa = (const float*)d_in[14];
    const float* ba = (const float*)d_in[15];
    const float* Wb = (const float*)d_in[16];
    const float* bb = (const float*)d_in[17];
    const float* Wc = (const float*)d_in[18];
    float* out = (float*)d_out;

    char* w = (char*)d_ws;
    size_t off = 0;
    auto alloc = [&](size_t bytes) -> void* {
        void* p = w + off;
        off = (off + bytes + 255) & ~(size_t)255;
        return p;
    };
    int*   rp    = (int*)alloc((NNODE + 1) * 4);
    int*   csr   = (int*)alloc(NEDGE * 4);
    float* dinv  = (float*)alloc(NNODE * 4);
    float* gate  = (float*)alloc(NNODE * 4);
    float* spart = (float*)alloc((size_t)2 * NNODE * 4);
    float* qinv  = (float*)alloc(256);
    int*   alive = (int*)alloc(NNODE * 4);
    float* hbuf  = (float*)alloc((size_t)NNODE * 128 * 4);
    _Float16* xh = (_Float16*)alloc((size_t)NNODE * 128 * 2);
    _Float16* xl = (_Float16*)alloc((size_t)NNODE * 128 * 2);
    float* hg    = (float*)alloc(NGRAPH * 256 * 4);
    _Float16* wfh = (_Float16*)alloc(3 * 16384 * 2);
    _Float16* wfl = (_Float16*)alloc(3 * 16384 * 2);

    k_csr<<<225, 512, 0, stream>>>(srcE, dstE, rp, csr, gate, alive, dinv, hg,
                                   Wl[0], Wl[1], Wl[2], wfh, wfl, Pl[0], Pl[1], Pl[2], qinv);

    // L1
    k_gemm<<<512, 256, 0, stream>>>(x_in, xh, xl, wfh, wfl, gate, alive, hbuf, 1, 512);
    k_aggL<<<256, 1024, 0, stream>>>(hbuf, dinv, rp, csr, alive, bl[0], Pl[0], xh, xl, spart, 512);
    k_poolA<<<NGRAPH, 512, 0, stream>>>(xh, xl, spart, qinv, 0, gate, alive, hg, rp, csr, dinv, 256, 0);

    // L2 (pool2 carries gemm L3)
    k_gemm<<<256, 256, 0, stream>>>(x_in, xh, xl, wfh + 16384, wfl + 16384, gate, alive, hbuf, 0, 256);
    k_aggS<<<256, 1024, 0, stream>>>(hbuf, dinv, rp, csr, alive, bl[1], Pl[1], xh, xl, spart, 256);
    k_poolB<<<NGRAPH, 512, 0, stream>>>(xh, xl, spart, qinv, 1, gate, alive, hg, rp, csr, dinv, 128, 0,
                                        wfh + 32768, wfl + 32768, hbuf);

    // L3 (pool3 carries MLP head)
    k_aggS<<<256, 1024, 0, stream>>>(hbuf, dinv, rp, csr, alive, bl[2], Pl[2], xh, xl, spart, 128);
    k_poolC<<<NGRAPH, 512, 0, stream>>>(xh, xl, spart, qinv, 2, gate, alive, hg, rp, csr, dinv, 64, 1,
                                        inp_c, We, Wa, ba, Wb, bb, Wc, out);
}